// Round 1
// baseline (67686.780 us; speedup 1.0000x reference)
//
#include <hip/hip_runtime.h>
#include <hip/hip_bf16.h>

#define NN 1024
#define NROWS 32                 // Whh rows per scan workgroup
#define SCAN_S 1026              // padded LDS row stride in floats (breaks bank conflicts, keeps 8B align)
#define SCAN_LDS_BYTES ((NROWS * SCAN_S + NN + 256) * 4)

// Static device scratch (avoids any dependence on ws_size).
__device__ float g_U[NN * NN];
__device__ float g_b0[NN * NN];
__device__ float g_b1[NN * NN];
__device__ unsigned long long g_hx[2 * NN];   // packed {tag, h} exchange slots, parity double-buffered

__device__ __forceinline__ float* dev_buf(int sel) {
  return sel == 0 ? g_U : (sel == 1 ? g_b0 : g_b1);
}

__global__ void k_init() {
  const int t = threadIdx.x;
  for (int i = t; i < 2 * NN; i += 256)
    __hip_atomic_store(&g_hx[i], 0ull, __ATOMIC_RELAXED, __HIP_MEMORY_SCOPE_AGENT);
}

// C[m][n] = sum_k A[m][k] * B[n][k] + b1[n] (+ b2[n])
// A: pitch lda, B: row-major [NN][NN], C: pitch ldc. asel/csel >=0 pick a static device buffer.
__global__ __launch_bounds__(256) void k_gemm(
    const float* __restrict__ Aext, int asel, long lda,
    const float* __restrict__ B,
    const float* __restrict__ b1, const float* __restrict__ b2,
    float* __restrict__ Cext, int csel, long ldc)
{
  const float* A = (asel < 0) ? Aext : dev_buf(asel);
  float* C = (csel < 0) ? Cext : dev_buf(csel);
  __shared__ float sA[16][68];
  __shared__ float sB[16][68];
  const int tid = threadIdx.x;
  const int tx = tid & 15, ty = tid >> 4;
  const int bm = blockIdx.y << 6, bn = blockIdx.x << 6;
  const int lm = tid & 63;
  const int lk = (tid >> 6) << 2;
  float acc[4][4] = {};
  for (int k0 = 0; k0 < NN; k0 += 16) {
    const float4 av = *(const float4*)&A[(long)(bm + lm) * lda + k0 + lk];
    const float4 bv = *(const float4*)&B[(long)(bn + lm) * NN + k0 + lk];
    __syncthreads();
    sA[lk + 0][lm] = av.x; sA[lk + 1][lm] = av.y; sA[lk + 2][lm] = av.z; sA[lk + 3][lm] = av.w;
    sB[lk + 0][lm] = bv.x; sB[lk + 1][lm] = bv.y; sB[lk + 2][lm] = bv.z; sB[lk + 3][lm] = bv.w;
    __syncthreads();
    #pragma unroll
    for (int kk = 0; kk < 16; ++kk) {
      const float4 a4 = *(const float4*)&sA[kk][ty << 2];
      const float4 b4 = *(const float4*)&sB[kk][tx << 2];
      const float aa[4] = {a4.x, a4.y, a4.z, a4.w};
      const float bb[4] = {b4.x, b4.y, b4.z, b4.w};
      #pragma unroll
      for (int i = 0; i < 4; ++i)
        #pragma unroll
        for (int j = 0; j < 4; ++j)
          acc[i][j] += aa[i] * bb[j];
    }
  }
  const int n0 = bn + (tx << 2);
  float bias[4];
  #pragma unroll
  for (int j = 0; j < 4; ++j) {
    bias[j] = b1[n0 + j];
    if (b2) bias[j] += b2[n0 + j];
  }
  #pragma unroll
  for (int i = 0; i < 4; ++i) {
    const int m = bm + (ty << 2) + i;
    float4 o;
    o.x = acc[i][0] + bias[0]; o.y = acc[i][1] + bias[1];
    o.z = acc[i][2] + bias[2]; o.w = acc[i][3] + bias[3];
    *(float4*)&C[(long)m * ldc + n0] = o;
  }
}

// Sequential recurrence over s=0..1023 for one layer:
//   h_s = tanh(U[s] + Whh * h_{s-1}),  h_{-1} = 0
// 32 WGs, WG b owns output rows [32b, 32b+32). Whh rows staged in LDS once.
// Cross-WG h exchange: 64-bit {tag,value} agent-scope atomics, parity double-buffered, fence-free.
__global__ __launch_bounds__(256, 1) void k_scan(const float* __restrict__ Whh, int osel, int layer) {
  extern __shared__ float smem[];
  float* sW = smem;                       // [NROWS][SCAN_S]
  float* sh = smem + NROWS * SCAN_S;      // [NN] gathered h_{s-1}
  float* sp = sh + NN;                    // [256] partial dots
  float* Out = dev_buf(osel);
  const int tid = threadIdx.x;
  const int woff = blockIdx.x * NROWS;

  // Stage this WG's Whh rows into LDS (padded stride).
  for (int j = tid * 4; j < NROWS * NN; j += 256 * 4) {
    const int m = j >> 10, k = j & (NN - 1);
    const float4 w = *(const float4*)&Whh[(long)(woff + m) * NN + k];
    float* d = &sW[m * SCAN_S + k];
    d[0] = w.x; d[1] = w.y; d[2] = w.z; d[3] = w.w;
  }
  __syncthreads();

  const int r = tid & 31, c = tid >> 5;   // r: row within WG, c: 128-col chunk
  const unsigned base_tag = (unsigned)layer * 1024u + 1u;

  for (int s = 0; s < NN; ++s) {
    float u = 0.f;
    if (tid < 32) u = g_U[s * NN + woff + tid];   // prefetchable, independent of h
    float dot = 0.f;
    if (s > 0) {
      // Gather all 1024 h_{s-1} values; spin on tag equality (data travels in the atomic).
      const unsigned tag = base_tag + (unsigned)(s - 1);
      unsigned long long* src = &g_hx[((s - 1) & 1) * NN];
      unsigned done = 0;
      while (done != 0xFu) {
        #pragma unroll
        for (int i = 0; i < 4; ++i) {
          if (!(done & (1u << i))) {
            const int q = tid + (i << 8);
            const unsigned long long v =
                __hip_atomic_load(&src[q], __ATOMIC_RELAXED, __HIP_MEMORY_SCOPE_AGENT);
            if ((unsigned)(v >> 32) == tag) {
              sh[q] = __uint_as_float((unsigned)v);
              done |= 1u << i;
            }
          }
        }
      }
      __syncthreads();
      // Partial dot: row r, columns [c*128, c*128+128)
      float acc = 0.f;
      const float* wr = &sW[r * SCAN_S + (c << 7)];
      const float* hr = &sh[c << 7];
      #pragma unroll 16
      for (int k = 0; k < 128; k += 2) {
        const float2 w2 = *(const float2*)&wr[k];
        const float2 h2 = *(const float2*)&hr[k];
        acc += w2.x * h2.x + w2.y * h2.y;
      }
      sp[c * 32 + r] = acc;
      __syncthreads();
      if (tid < 32) {
        #pragma unroll
        for (int cc = 0; cc < 8; ++cc) dot += sp[cc * 32 + tid];
      }
    }
    if (tid < 32) {
      const float h = tanhf(u + dot);
      Out[s * NN + woff + tid] = h;     // stream output for next layer's GEMM
      const unsigned long long pv =
          ((unsigned long long)(base_tag + (unsigned)s) << 32) |
          (unsigned long long)__float_as_uint(h);
      __hip_atomic_store(&g_hx[(s & 1) * NN + woff + tid], pv,
                         __ATOMIC_RELAXED, __HIP_MEMORY_SCOPE_AGENT);
    }
    __syncthreads();   // protect sh/sp reuse next iteration
  }
}

extern "C" void kernel_launch(void* const* d_in, const int* in_sizes, int n_in,
                              void* d_out, int out_size, void* d_ws, size_t ws_size,
                              hipStream_t stream) {
  (void)in_sizes; (void)n_in; (void)out_size; (void)d_ws; (void)ws_size;
  const float* x    = (const float*)d_in[0];
  const float* Wih  = (const float*)d_in[1];
  const float* Whh  = (const float*)d_in[2];
  const float* bih  = (const float*)d_in[3];
  const float* bhh  = (const float*)d_in[4];
  const float* linW = (const float*)d_in[5];
  const float* linb = (const float*)d_in[6];
  float* out = (float*)d_out;

  (void)hipFuncSetAttribute((const void*)k_scan,
                            hipFuncAttributeMaxDynamicSharedMemorySize, SCAN_LDS_BYTES);

  k_init<<<1, 256, 0, stream>>>();

  const dim3 ggrid(16, 16);
  const float* Aext = x; int asel = -1; long lda = 8 * NN;  // x[s,0,:] pitch = T*N
  for (int t = 0; t < 8; ++t) {
    for (int l = 0; l < 2; ++l) {
      const int L = t * 2 + l;
      // U = In * Wih^T + bih + bhh  -> g_U
      k_gemm<<<ggrid, 256, 0, stream>>>(Aext, asel, lda,
          Wih + (size_t)L * NN * NN, bih + (size_t)L * NN, bhh + (size_t)L * NN,
          nullptr, 0, NN);
      const int osel = (l == 0) ? 1 : 2;
      k_scan<<<32, 256, SCAN_LDS_BYTES, stream>>>(Whh + (size_t)L * NN * NN, osel, L);
      Aext = nullptr; asel = osel; lda = NN;
    }
    // Linear: out[:, t, :] = In * linW^T + linb  (also the input of layer (t+1, 0))
    k_gemm<<<ggrid, 256, 0, stream>>>(nullptr, asel, lda,
        linW + (size_t)t * NN * NN, linb + (size_t)t * NN, nullptr,
        out + (size_t)t * NN, -1, 8 * NN);
    Aext = out + (size_t)t * NN; asel = -1; lda = 8 * NN;
  }
}

// Round 2
// 4870.326 us; speedup vs baseline: 13.8978x; 13.8978x over previous
//
#include <hip/hip_runtime.h>
#include <hip/hip_fp16.h>

#define NN 1024
#define RSH 2050              // LDS weight row stride in halves: word-stride 1025 (odd) -> conflict-free
#define PH_THREADS 512
#define PH_SMEM (32 * RSH * 2 + 2048 * 2 + 512 * 4)   // 137,344 B

typedef _Float16 v2h __attribute__((ext_vector_type(2)));

// Static device scratch.
__device__ __half g_W[16][NN][2048];            // per stage: [Wih_eff | Whh] fp16
__device__ float g_bias[16][NN];                // per stage: combined bias fp32
__device__ unsigned long long g_H[16][NN * NN]; // {marker<<32 | f32 h} exchange slots
__device__ float g_Hout[8][NN * NN];            // h of odd stages (pre-linear), fp32

// ---- zero the exchange markers (required every launch for replay determinism) ----
__global__ void k_init() {
  const size_t n = (size_t)16 * NN * NN;
  size_t i = (size_t)blockIdx.x * blockDim.x + threadIdx.x;
  const size_t stride = (size_t)gridDim.x * blockDim.x;
  unsigned long long* p = &g_H[0][0];
  for (; i < n; i += stride) p[i] = 0ull;
}

// ---- pack Whh (all stages) and Wih (non-folded stages) to fp16 ----
__global__ void k_pack(const float* __restrict__ Wih, const float* __restrict__ Whh) {
  const size_t total = (size_t)16 * NN * NN;
  size_t i = (size_t)blockIdx.x * blockDim.x + threadIdx.x;
  const size_t stride = (size_t)gridDim.x * blockDim.x;
  for (; i < total; i += stride) {
    const int st = (int)(i >> 20);
    const int m = (int)(i >> 10) & 1023;
    const int k = (int)i & 1023;
    g_W[st][m][1024 + k] = __float2half(Whh[i]);
    const int t = st >> 1, l = st & 1;
    if (l == 1 || t == 0) g_W[st][m][k] = __float2half(Wih[i]);
  }
}

// ---- fold: W'(st=2t) = Wih[st] @ linW[t-1]  (nn GEMM, fp32 accum -> fp16) ----
__global__ __launch_bounds__(256) void k_fold(const float* __restrict__ Wih,
                                              const float* __restrict__ linW) {
  const int tm1 = blockIdx.z;            // t-1 in 0..6
  const int st = (tm1 + 1) * 2;
  const float* A = Wih + (size_t)st * NN * NN;    // [m][j]
  const float* B = linW + (size_t)tm1 * NN * NN;  // [j][k]
  __shared__ float sA[16][68];
  __shared__ float sB[16][68];
  const int tid = threadIdx.x;
  const int tx = tid & 15, ty = tid >> 4;
  const int bm = blockIdx.y << 6, bn = blockIdx.x << 6;
  const int lm = tid & 63, lk = (tid >> 6) << 2;
  const int rr = tid >> 4, c4 = (tid & 15) << 2;
  float acc[4][4] = {};
  for (int k0 = 0; k0 < NN; k0 += 16) {
    const float4 av = *(const float4*)&A[(size_t)(bm + lm) * NN + k0 + lk];
    const float4 bv = *(const float4*)&B[(size_t)(k0 + rr) * NN + bn + c4];
    __syncthreads();
    sA[lk + 0][lm] = av.x; sA[lk + 1][lm] = av.y; sA[lk + 2][lm] = av.z; sA[lk + 3][lm] = av.w;
    sB[rr][c4 + 0] = bv.x; sB[rr][c4 + 1] = bv.y; sB[rr][c4 + 2] = bv.z; sB[rr][c4 + 3] = bv.w;
    __syncthreads();
    #pragma unroll
    for (int kk = 0; kk < 16; ++kk) {
      const float4 a4 = *(const float4*)&sA[kk][ty << 2];
      const float4 b4 = *(const float4*)&sB[kk][tx << 2];
      const float aa[4] = {a4.x, a4.y, a4.z, a4.w};
      const float bb[4] = {b4.x, b4.y, b4.z, b4.w};
      #pragma unroll
      for (int i = 0; i < 4; ++i)
        #pragma unroll
        for (int j = 0; j < 4; ++j) acc[i][j] += aa[i] * bb[j];
    }
  }
  #pragma unroll
  for (int i = 0; i < 4; ++i)
    #pragma unroll
    for (int j = 0; j < 4; ++j)
      g_W[st][bm + (ty << 2) + i][bn + (tx << 2) + j] = __float2half(acc[i][j]);
}

// ---- combined bias per stage: bih+bhh (+ Wih @ linb[t-1] for folded stages) ----
__global__ __launch_bounds__(256) void k_bias(const float* __restrict__ Wih,
    const float* __restrict__ bih, const float* __restrict__ bhh,
    const float* __restrict__ linb) {
  const int st = blockIdx.x, t = st >> 1, l = st & 1;
  const int tid = threadIdx.x;
  __shared__ float slb[NN];
  const bool folded = (l == 0 && t > 0);
  if (folded)
    for (int k = tid; k < NN; k += 256) slb[k] = linb[(size_t)(t - 1) * NN + k];
  __syncthreads();
  for (int m = tid; m < NN; m += 256) {
    float b = bih[(size_t)st * NN + m] + bhh[(size_t)st * NN + m];
    if (folded) {
      const float* wr = Wih + (size_t)st * NN * NN + (size_t)m * NN;
      float s0 = 0, s1 = 0, s2 = 0, s3 = 0;
      for (int k = 0; k < NN; k += 4) {
        const float4 w = *(const float4*)&wr[k];
        s0 += w.x * slb[k]; s1 += w.y * slb[k + 1];
        s2 += w.z * slb[k + 2]; s3 += w.w * slb[k + 3];
      }
      b += (s0 + s1) + (s2 + s3);
    }
    g_bias[st][m] = b;
  }
}

// ---- pipelined 8-stage scan: 256 WGs (stage = bid>>5), 1 WG/CU (LDS-forced) ----
// All 256 WGs place immediately at dispatch (exact fit), so cross-WG spins cannot deadlock.
__global__ __launch_bounds__(PH_THREADS, 1) void k_phase(const float* __restrict__ x,
                                                         int stage_base) {
  extern __shared__ __align__(16) unsigned char smem[];
  __half* sW = (__half*)smem;                              // [32][RSH]
  __half* sh = (__half*)(smem + 32 * RSH * 2);             // [2048] = [x_s | h_{s-1}]
  float* sp = (float*)(smem + 32 * RSH * 2 + 2048 * 2);    // [16][32]
  const int tid = threadIdx.x;
  const int st = stage_base + ((int)blockIdx.x >> 5);
  const int woff = ((int)blockIdx.x & 31) << 5;

  // Stage 32 rows x 2048 halves of fp16 weights into LDS (stride RSH).
  for (int j = tid * 4; j < 32 * 2048; j += PH_THREADS * 4) {
    const int m = j >> 11, k = j & 2047;
    const uint2 w = *(const uint2*)&g_W[st][woff + m][k];
    unsigned* dst = (unsigned*)&sW[m * RSH + k];
    dst[0] = w.x; dst[1] = w.y;
  }
  float breg = 0.f;
  if (tid < 32) breg = g_bias[st][woff + tid];

  unsigned long long* ownbuf = g_H[st];
  unsigned long long* upbuf = (st > 0) ? g_H[st - 1] : nullptr;
  const int q2 = tid * 2;
  const int r = tid & 31, c = tid >> 5;    // output row, 128-col chunk (16 chunks)
  __syncthreads();

  for (int s = 0; s < NN; ++s) {
    // ---- gather x_s (upstream) and h_{s-1} (own) into sh as fp16 ----
    if (st == 0) {
      const float2 xv = *(const float2*)&x[(size_t)s * 8192 + q2];
      v2h hv; hv.x = (_Float16)xv.x; hv.y = (_Float16)xv.y;
      *(v2h*)&sh[q2] = hv;
    }
    if (s == 0) *(unsigned*)&sh[1024 + q2] = 0u;
    unsigned need = (st != 0 ? 0x3u : 0u) | (s != 0 ? 0xCu : 0u);
    unsigned done = 0;
    while (done != need) {
      if ((need & 0x3u) != (done & 0x3u)) {
        #pragma unroll
        for (int i = 0; i < 2; ++i)
          if (!(done & (1u << i))) {
            const unsigned long long v = __hip_atomic_load(
                &upbuf[(size_t)s * NN + q2 + i], __ATOMIC_RELAXED, __HIP_MEMORY_SCOPE_AGENT);
            if (v >> 32) { sh[q2 + i] = __float2half(__uint_as_float((unsigned)v)); done |= 1u << i; }
          }
      }
      if ((need & 0xCu) != (done & 0xCu)) {
        #pragma unroll
        for (int i = 0; i < 2; ++i)
          if (!(done & (4u << i))) {
            const unsigned long long v = __hip_atomic_load(
                &ownbuf[(size_t)(s - 1) * NN + q2 + i], __ATOMIC_RELAXED, __HIP_MEMORY_SCOPE_AGENT);
            if (v >> 32) { sh[1024 + q2 + i] = __float2half(__uint_as_float((unsigned)v)); done |= 4u << i; }
          }
      }
      if (done != need) __builtin_amdgcn_s_sleep(1);
    }
    __syncthreads();
    // ---- matvec: row r, cols [c*128, c*128+128) of 2048; fp16 dot2, fp32 accum ----
    const __half* wr = &sW[r * RSH + (c << 7)];
    const v2h* vp = (const v2h*)&sh[c << 7];
    float a0 = 0, a1 = 0, a2 = 0, a3 = 0;
    #pragma unroll
    for (int k = 0; k < 64; k += 4) {
      a0 = __builtin_amdgcn_fdot2(*(const v2h*)&wr[2 * k + 0], vp[k + 0], a0, false);
      a1 = __builtin_amdgcn_fdot2(*(const v2h*)&wr[2 * k + 2], vp[k + 1], a1, false);
      a2 = __builtin_amdgcn_fdot2(*(const v2h*)&wr[2 * k + 4], vp[k + 2], a2, false);
      a3 = __builtin_amdgcn_fdot2(*(const v2h*)&wr[2 * k + 6], vp[k + 3], a3, false);
    }
    sp[c * 32 + r] = (a0 + a1) + (a2 + a3);
    __syncthreads();
    if (tid < 32) {
      float dot = breg;
      #pragma unroll
      for (int cc = 0; cc < 16; ++cc) dot += sp[cc * 32 + tid];
      const float h = tanhf(dot);
      const unsigned long long pv =
          (1ull << 32) | (unsigned long long)__float_as_uint(h);
      __hip_atomic_store(&ownbuf[(size_t)s * NN + woff + tid], pv,
                         __ATOMIC_RELAXED, __HIP_MEMORY_SCOPE_AGENT);
      if (st & 1) g_Hout[st >> 1][(size_t)s * NN + woff + tid] = h;
    }
    __syncthreads();
  }
}

// ---- epilogue: out[s][t][:] = g_Hout[t][s] @ linW[t]^T + linb[t], batched over t ----
__global__ __launch_bounds__(256) void k_out(const float* __restrict__ linW,
    const float* __restrict__ linb, float* __restrict__ out) {
  const int t = blockIdx.z;
  const float* A = g_Hout[t];
  const float* B = linW + (size_t)t * NN * NN;
  __shared__ float sA[16][68];
  __shared__ float sB[16][68];
  const int tid = threadIdx.x;
  const int tx = tid & 15, ty = tid >> 4;
  const int bm = blockIdx.y << 6, bn = blockIdx.x << 6;
  const int lm = tid & 63, lk = (tid >> 6) << 2;
  float acc[4][4] = {};
  for (int k0 = 0; k0 < NN; k0 += 16) {
    const float4 av = *(const float4*)&A[(size_t)(bm + lm) * NN + k0 + lk];
    const float4 bv = *(const float4*)&B[(size_t)(bn + lm) * NN + k0 + lk];
    __syncthreads();
    sA[lk + 0][lm] = av.x; sA[lk + 1][lm] = av.y; sA[lk + 2][lm] = av.z; sA[lk + 3][lm] = av.w;
    sB[lk + 0][lm] = bv.x; sB[lk + 1][lm] = bv.y; sB[lk + 2][lm] = bv.z; sB[lk + 3][lm] = bv.w;
    __syncthreads();
    #pragma unroll
    for (int kk = 0; kk < 16; ++kk) {
      const float4 a4 = *(const float4*)&sA[kk][ty << 2];
      const float4 b4 = *(const float4*)&sB[kk][tx << 2];
      const float aa[4] = {a4.x, a4.y, a4.z, a4.w};
      const float bb[4] = {b4.x, b4.y, b4.z, b4.w};
      #pragma unroll
      for (int i = 0; i < 4; ++i)
        #pragma unroll
        for (int j = 0; j < 4; ++j) acc[i][j] += aa[i] * bb[j];
    }
  }
  const int n0 = bn + (tx << 2);
  float bias[4];
  #pragma unroll
  for (int j = 0; j < 4; ++j) bias[j] = linb[(size_t)t * NN + n0 + j];
  #pragma unroll
  for (int i = 0; i < 4; ++i) {
    const int m = bm + (ty << 2) + i;
    float4 o;
    o.x = acc[i][0] + bias[0]; o.y = acc[i][1] + bias[1];
    o.z = acc[i][2] + bias[2]; o.w = acc[i][3] + bias[3];
    *(float4*)&out[(size_t)m * 8192 + (size_t)t * NN + n0] = o;
  }
}

extern "C" void kernel_launch(void* const* d_in, const int* in_sizes, int n_in,
                              void* d_out, int out_size, void* d_ws, size_t ws_size,
                              hipStream_t stream) {
  (void)in_sizes; (void)n_in; (void)out_size; (void)d_ws; (void)ws_size;
  const float* x    = (const float*)d_in[0];
  const float* Wih  = (const float*)d_in[1];
  const float* Whh  = (const float*)d_in[2];
  const float* bih  = (const float*)d_in[3];
  const float* bhh  = (const float*)d_in[4];
  const float* linW = (const float*)d_in[5];
  const float* linb = (const float*)d_in[6];
  float* out = (float*)d_out;

  (void)hipFuncSetAttribute((const void*)k_phase,
                            hipFuncAttributeMaxDynamicSharedMemorySize, PH_SMEM);

  k_init<<<2048, 256, 0, stream>>>();
  k_pack<<<2048, 256, 0, stream>>>(Wih, Whh);
  k_fold<<<dim3(16, 16, 7), 256, 0, stream>>>(Wih, linW);
  k_bias<<<16, 256, 0, stream>>>(Wih, bih, bhh, linb);
  k_phase<<<256, PH_THREADS, PH_SMEM, stream>>>(x, 0);   // stages 0..7  (t=0..3)
  k_phase<<<256, PH_THREADS, PH_SMEM, stream>>>(x, 8);   // stages 8..15 (t=4..7)
  k_out<<<dim3(16, 16, 8), 256, 0, stream>>>(linW, linb, out);
}

// Round 3
// 4823.272 us; speedup vs baseline: 14.0334x; 1.0098x over previous
//
#include <hip/hip_runtime.h>
#include <hip/hip_fp16.h>

#define NN 1024

typedef _Float16 v2h __attribute__((ext_vector_type(2)));
typedef unsigned int uint;
typedef unsigned long long u64;

// Static device scratch.
__device__ __half g_W[16][NN][2048];     // per stage row: [Wih_eff(1024) | Whh(1024)] fp16
__device__ float g_bias[16][NN];         // combined bias fp32
__device__ u64 g_S[16][NN][512];         // {tag32, fp16 h[2r+1], fp16 h[2r]} exchange slots
__device__ float g_Hout[8][NN * NN];     // h of odd stages (pre-linear), fp32

__device__ __forceinline__ v2h as_v2h(uint u) {
  union { uint u; v2h h; } c; c.u = u; return c.h;
}
__device__ __forceinline__ uint as_uint(v2h h) {
  union { v2h h; uint u; } c; c.h = h; return c.u;
}

// ---- zero exchange tags (every launch, replay determinism) ----
__global__ void k_init() {
  const size_t n = (size_t)16 * NN * 512;
  size_t i = (size_t)blockIdx.x * blockDim.x + threadIdx.x;
  const size_t stride = (size_t)gridDim.x * blockDim.x;
  u64* p = &g_S[0][0][0];
  for (; i < n; i += stride) p[i] = 0ull;
}

// ---- pack Whh (all stages) and Wih (non-folded stages) to fp16 ----
__global__ void k_pack(const float* __restrict__ Wih, const float* __restrict__ Whh) {
  const size_t total = (size_t)16 * NN * NN;
  size_t i = (size_t)blockIdx.x * blockDim.x + threadIdx.x;
  const size_t stride = (size_t)gridDim.x * blockDim.x;
  for (; i < total; i += stride) {
    const int st = (int)(i >> 20);
    const int m = (int)(i >> 10) & 1023;
    const int k = (int)i & 1023;
    g_W[st][m][1024 + k] = __float2half(Whh[i]);
    const int t = st >> 1, l = st & 1;
    if (l == 1 || t == 0) g_W[st][m][k] = __float2half(Wih[i]);
  }
}

// ---- fold: W'(st=2t) = Wih[st] @ linW[t-1] ----
__global__ __launch_bounds__(256) void k_fold(const float* __restrict__ Wih,
                                              const float* __restrict__ linW) {
  const int tm1 = blockIdx.z;
  const int st = (tm1 + 1) * 2;
  const float* A = Wih + (size_t)st * NN * NN;
  const float* B = linW + (size_t)tm1 * NN * NN;
  __shared__ float sA[16][68];
  __shared__ float sB[16][68];
  const int tid = threadIdx.x;
  const int tx = tid & 15, ty = tid >> 4;
  const int bm = blockIdx.y << 6, bn = blockIdx.x << 6;
  const int lm = tid & 63, lk = (tid >> 6) << 2;
  const int rr = tid >> 4, c4 = (tid & 15) << 2;
  float acc[4][4] = {};
  for (int k0 = 0; k0 < NN; k0 += 16) {
    const float4 av = *(const float4*)&A[(size_t)(bm + lm) * NN + k0 + lk];
    const float4 bv = *(const float4*)&B[(size_t)(k0 + rr) * NN + bn + c4];
    __syncthreads();
    sA[lk + 0][lm] = av.x; sA[lk + 1][lm] = av.y; sA[lk + 2][lm] = av.z; sA[lk + 3][lm] = av.w;
    sB[rr][c4 + 0] = bv.x; sB[rr][c4 + 1] = bv.y; sB[rr][c4 + 2] = bv.z; sB[rr][c4 + 3] = bv.w;
    __syncthreads();
    #pragma unroll
    for (int kk = 0; kk < 16; ++kk) {
      const float4 a4 = *(const float4*)&sA[kk][ty << 2];
      const float4 b4 = *(const float4*)&sB[kk][tx << 2];
      const float aa[4] = {a4.x, a4.y, a4.z, a4.w};
      const float bb[4] = {b4.x, b4.y, b4.z, b4.w};
      #pragma unroll
      for (int i = 0; i < 4; ++i)
        #pragma unroll
        for (int j = 0; j < 4; ++j) acc[i][j] += aa[i] * bb[j];
    }
  }
  #pragma unroll
  for (int i = 0; i < 4; ++i)
    #pragma unroll
    for (int j = 0; j < 4; ++j)
      g_W[st][bm + (ty << 2) + i][bn + (tx << 2) + j] = __float2half(acc[i][j]);
}

// ---- combined bias per stage ----
__global__ __launch_bounds__(256) void k_bias(const float* __restrict__ Wih,
    const float* __restrict__ bih, const float* __restrict__ bhh,
    const float* __restrict__ linb) {
  const int st = blockIdx.x, t = st >> 1, l = st & 1;
  const int tid = threadIdx.x;
  __shared__ float slb[NN];
  const bool folded = (l == 0 && t > 0);
  if (folded)
    for (int k = tid; k < NN; k += 256) slb[k] = linb[(size_t)(t - 1) * NN + k];
  __syncthreads();
  for (int m = tid; m < NN; m += 256) {
    float b = bih[(size_t)st * NN + m] + bhh[(size_t)st * NN + m];
    if (folded) {
      const float* wr = Wih + (size_t)st * NN * NN + (size_t)m * NN;
      float s0 = 0, s1 = 0, s2 = 0, s3 = 0;
      for (int k = 0; k < NN; k += 4) {
        const float4 w = *(const float4*)&wr[k];
        s0 += w.x * slb[k]; s1 += w.y * slb[k + 1];
        s2 += w.z * slb[k + 2]; s3 += w.w * slb[k + 3];
      }
      b += (s0 + s1) + (s2 + s3);
    }
    g_bias[st][m] = b;
  }
}

// ---- pipelined 16-stage scan, weights in VGPRs, one dispatch ----
// 512 WGs: stage = bid>>5 (0..15), WG-in-stage = bid&31 owns rows [32wg, 32wg+32).
// Thread (r=tid>>4, c=tid&15): row woff+r, col-chunk c (64 halves of each matrix) in regs.
// Deadlock-free for ANY residency: producers never wait on consumers; blocks place in bid order.
__global__ __launch_bounds__(512, 4) void k_phase(const float* __restrict__ x) {
  __shared__ __align__(16) __half shx[2][NN];
  __shared__ __align__(16) __half shh[2][NN];
  const int tid = threadIdx.x;
  const int bid = blockIdx.x;
  const int st = bid >> 5;
  const int wg = bid & 31;
  const int woff = wg << 5;
  const int r = tid >> 4;
  const int c = tid & 15;
  const int q = tid;                       // slot 0..511 this thread gathers

  // Persistent weight slice: 64 halves Wih + 64 halves Whh.
  uint4 wxr[8], whr[8];
  {
    const __half* wrow = &g_W[st][woff + r][0];
    #pragma unroll
    for (int j = 0; j < 8; ++j) {
      wxr[j] = *(const uint4*)&wrow[c * 64 + 8 * j];
      whr[j] = *(const uint4*)&wrow[1024 + c * 64 + 8 * j];
    }
  }
  const float breg = g_bias[st][woff + r];

  const u64* ph = &g_S[st][0][q];                         // + (s-1)*512
  const u64* px = (st > 0) ? &g_S[st - 1][0][q] : nullptr; // + s*512
  const int isPub = ((tid & 31) == 0);
  const int slot = wg * 16 + ((tid >> 6) << 1) + ((tid >> 5) & 1);
  u64* pw = &g_S[st][0][slot];                             // + s*512
  float* hout = (st & 1) ? &g_Hout[st >> 1][0] : nullptr;
  const int hrow = woff + ((tid >> 6) << 2) + (((tid >> 5) & 1) << 1);

  const int cc = q >> 5;                                   // write chunk
  const int wroff = cc * 64 + (((2 * q) + 8 * cc) & 63);   // swizzled LDS write offset
  const int cswz = 8 * c;                                  // read swizzle rotation

  float2 xcur;
  if (st == 0) xcur = *(const float2*)&x[2 * q];

  for (int s = 0; s < NN; ++s) {
    const int b = s & 1;
    // ---------- phase A: gather inputs ----------
    uint dh = 0, dx = 0;
    bool hp = (s > 0);
    bool xp = (st > 0);
    if (st == 0) {
      v2h hv; hv.x = (_Float16)xcur.x; hv.y = (_Float16)xcur.y;
      dx = as_uint(hv);
      if (s + 1 < NN) xcur = *(const float2*)&x[(size_t)(s + 1) * 8192 + 2 * q];
    }
    const u64* ah = ph + (size_t)(s - 1) * 512;
    const u64* ax = (st > 0) ? px + (size_t)s * 512 : nullptr;
    while (hp || xp) {
      u64 vh = 0, vx = 0;
      if (hp) vh = __hip_atomic_load(ah, __ATOMIC_RELAXED, __HIP_MEMORY_SCOPE_AGENT);
      if (xp) vx = __hip_atomic_load(ax, __ATOMIC_RELAXED, __HIP_MEMORY_SCOPE_AGENT);
      if (hp && (vh >> 32)) { dh = (uint)vh; hp = false; }
      if (xp && (vx >> 32)) { dx = (uint)vx; xp = false; }
      if (hp || xp) __builtin_amdgcn_s_sleep(1);
    }
    *(uint*)&shh[b][wroff] = dh;
    *(uint*)&shx[b][wroff] = dx;
    __syncthreads();
    // ---------- phase B: dot from regs x LDS(b128, swizzled) ----------
    float acc = 0.f;
    const __half* bx = &shx[b][c * 64];
    const __half* bh = &shh[b][c * 64];
    #pragma unroll
    for (int j = 0; j < 8; ++j) {
      const uint4 v = *(const uint4*)&bx[(8 * j + cswz) & 63];
      acc = __builtin_amdgcn_fdot2(as_v2h(wxr[j].x), as_v2h(v.x), acc, false);
      acc = __builtin_amdgcn_fdot2(as_v2h(wxr[j].y), as_v2h(v.y), acc, false);
      acc = __builtin_amdgcn_fdot2(as_v2h(wxr[j].z), as_v2h(v.z), acc, false);
      acc = __builtin_amdgcn_fdot2(as_v2h(wxr[j].w), as_v2h(v.w), acc, false);
    }
    #pragma unroll
    for (int j = 0; j < 8; ++j) {
      const uint4 v = *(const uint4*)&bh[(8 * j + cswz) & 63];
      acc = __builtin_amdgcn_fdot2(as_v2h(whr[j].x), as_v2h(v.x), acc, false);
      acc = __builtin_amdgcn_fdot2(as_v2h(whr[j].y), as_v2h(v.y), acc, false);
      acc = __builtin_amdgcn_fdot2(as_v2h(whr[j].z), as_v2h(v.z), acc, false);
      acc = __builtin_amdgcn_fdot2(as_v2h(whr[j].w), as_v2h(v.w), acc, false);
    }
    // 16-lane butterfly reduce (col-threads of a row), + bias, tanh
    acc += __shfl_xor(acc, 1);
    acc += __shfl_xor(acc, 2);
    acc += __shfl_xor(acc, 4);
    acc += __shfl_xor(acc, 8);
    const float hval = tanhf(acc + breg);
    const float hpair = __shfl_xor(hval, 16);   // row+1's value onto even-row lane
    if (isPub) {
      v2h p; p.x = (_Float16)hval; p.y = (_Float16)hpair;
      const u64 pv = (1ull << 32) | (u64)as_uint(p);
      __hip_atomic_store(pw + (size_t)s * 512, pv,
                         __ATOMIC_RELAXED, __HIP_MEMORY_SCOPE_AGENT);
      if (hout) *(float2*)&hout[(size_t)s * NN + hrow] = make_float2(hval, hpair);
    }
    // no trailing barrier: next phase A writes buffer b^1; shared reads of buffer b
    // are separated from the next write to b by the barrier inside phase A(s+1).
  }
}

// ---- epilogue: out[s][t][:] = g_Hout[t][s] @ linW[t]^T + linb[t] ----
__global__ __launch_bounds__(256) void k_out(const float* __restrict__ linW,
    const float* __restrict__ linb, float* __restrict__ out) {
  const int t = blockIdx.z;
  const float* A = g_Hout[t];
  const float* B = linW + (size_t)t * NN * NN;
  __shared__ float sA[16][68];
  __shared__ float sB[16][68];
  const int tid = threadIdx.x;
  const int tx = tid & 15, ty = tid >> 4;
  const int bm = blockIdx.y << 6, bn = blockIdx.x << 6;
  const int lm = tid & 63, lk = (tid >> 6) << 2;
  float acc[4][4] = {};
  for (int k0 = 0; k0 < NN; k0 += 16) {
    const float4 av = *(const float4*)&A[(size_t)(bm + lm) * NN + k0 + lk];
    const float4 bv = *(const float4*)&B[(size_t)(bn + lm) * NN + k0 + lk];
    __syncthreads();
    sA[lk + 0][lm] = av.x; sA[lk + 1][lm] = av.y; sA[lk + 2][lm] = av.z; sA[lk + 3][lm] = av.w;
    sB[lk + 0][lm] = bv.x; sB[lk + 1][lm] = bv.y; sB[lk + 2][lm] = bv.z; sB[lk + 3][lm] = bv.w;
    __syncthreads();
    #pragma unroll
    for (int kk = 0; kk < 16; ++kk) {
      const float4 a4 = *(const float4*)&sA[kk][ty << 2];
      const float4 b4 = *(const float4*)&sB[kk][tx << 2];
      const float aa[4] = {a4.x, a4.y, a4.z, a4.w};
      const float bb[4] = {b4.x, b4.y, b4.z, b4.w};
      #pragma unroll
      for (int i = 0; i < 4; ++i)
        #pragma unroll
        for (int j = 0; j < 4; ++j) acc[i][j] += aa[i] * bb[j];
    }
  }
  const int n0 = bn + (tx << 2);
  float bias[4];
  #pragma unroll
  for (int j = 0; j < 4; ++j) bias[j] = linb[(size_t)t * NN + n0 + j];
  #pragma unroll
  for (int i = 0; i < 4; ++i) {
    const int m = bm + (ty << 2) + i;
    float4 o;
    o.x = acc[i][0] + bias[0]; o.y = acc[i][1] + bias[1];
    o.z = acc[i][2] + bias[2]; o.w = acc[i][3] + bias[3];
    *(float4*)&out[(size_t)m * 8192 + (size_t)t * NN + n0] = o;
  }
}

extern "C" void kernel_launch(void* const* d_in, const int* in_sizes, int n_in,
                              void* d_out, int out_size, void* d_ws, size_t ws_size,
                              hipStream_t stream) {
  (void)in_sizes; (void)n_in; (void)out_size; (void)d_ws; (void)ws_size;
  const float* x    = (const float*)d_in[0];
  const float* Wih  = (const float*)d_in[1];
  const float* Whh  = (const float*)d_in[2];
  const float* bih  = (const float*)d_in[3];
  const float* bhh  = (const float*)d_in[4];
  const float* linW = (const float*)d_in[5];
  const float* linb = (const float*)d_in[6];
  float* out = (float*)d_out;

  k_init<<<2048, 256, 0, stream>>>();
  k_pack<<<2048, 256, 0, stream>>>(Wih, Whh);
  k_fold<<<dim3(16, 16, 7), 256, 0, stream>>>(Wih, linW);
  k_bias<<<16, 256, 0, stream>>>(Wih, bih, bhh, linb);
  k_phase<<<512, 512, 0, stream>>>(x);
  k_out<<<dim3(16, 16, 8), 256, 0, stream>>>(linW, linb, out);
}